// Round 2
// baseline (87.713 us; speedup 1.0000x reference)
//
#include <hip/hip_runtime.h>
#include <math.h>

#define U 50
#define TT 100
#define BB 256

__device__ __forceinline__ float sigmoid_fast(float x) {
    // 1/(1+exp(-x)); saturates cleanly, no NaN.
    return 1.0f / (1.0f + __expf(-x));
}
__device__ __forceinline__ float tanh_fast(float x) {
    // tanh(x) = 1 - 2/(exp(2x)+1); saturates cleanly, no NaN.
    float e = __expf(2.0f * x);
    return 1.0f - 2.0f / (e + 1.0f);
}
__device__ __forceinline__ float param_act(float x, float mn, float mx) {
    float scale = 0.5f * (mx - mn);
    return tanh_fast(x) * scale + mn + scale;
}

// One wave (64 threads) per batch element. Lane l (<50) owns LSTM unit l:
// all four gate columns in registers, gate math lane-local. Only h is
// exchanged, via LDS broadcast reads (no barrier needed: single wave,
// in-order LDS ops + compiler lgkmcnt).
__global__ __launch_bounds__(64, 1) void encoder_kernel(
    const float* __restrict__ x,        // (B,T,4)
    const float* __restrict__ state,    // (B,T,4)
    const float* __restrict__ kernel,   // (4,200)
    const float* __restrict__ rec,      // (50,200)
    const float* __restrict__ bias,     // (200,)
    const float* __restrict__ w_dv, const float* __restrict__ b_dv,
    const float* __restrict__ w_dt, const float* __restrict__ b_dt,
    const float* __restrict__ w_mj, const float* __restrict__ b_mj,
    const float* __restrict__ w_ma, const float* __restrict__ b_ma,
    const float* __restrict__ w_mi, const float* __restrict__ b_mi,
    float* __restrict__ out)            // act_seq (B*T) then idm (B*5)
{
    const int b = blockIdx.x;
    const int l = threadIdx.x;

    __shared__ __align__(16) float h_lds[52];   // 50 + 2 pad (pad stays 0)
    __shared__ float idm[8];

    const bool act_lane = (l < U);

    // Per-lane weights in registers: rc[g][j] = rec[j][g*50+l]
    float rc[4][U];
    float kc[4][4];
    float bz[4];
    #pragma unroll
    for (int g = 0; g < 4; ++g) {
        const int col = g * U + l;
        #pragma unroll
        for (int j = 0; j < U; ++j)
            rc[g][j] = act_lane ? rec[j * 200 + col] : 0.0f;
        #pragma unroll
        for (int f = 0; f < 4; ++f)
            kc[g][f] = act_lane ? kernel[f * 200 + col] : 0.0f;
        bz[g] = act_lane ? bias[col] : 0.0f;
    }

    if (l < 52) h_lds[l] = 0.0f;
    float c = 0.0f;

    const float4* __restrict__ xb4 = (const float4*)(x + (size_t)b * TT * 4);
    const float4* __restrict__ h4p = (const float4*)h_lds;

    for (int t = 0; t < TT; ++t) {
        // uniform load, consumed at the very end of the iteration -> latency hidden
        float4 x4 = xb4[t];

        float za[4] = {0.f, 0.f, 0.f, 0.f};
        float zb[4] = {0.f, 0.f, 0.f, 0.f};
        #pragma unroll
        for (int j4 = 0; j4 < 12; ++j4) {
            float4 h4 = h4p[j4];             // LDS broadcast (ds_read_b128)
            #pragma unroll
            for (int g = 0; g < 4; ++g) {
                za[g] = fmaf(h4.x, rc[g][4 * j4 + 0], za[g]);
                zb[g] = fmaf(h4.y, rc[g][4 * j4 + 1], zb[g]);
                za[g] = fmaf(h4.z, rc[g][4 * j4 + 2], za[g]);
                zb[g] = fmaf(h4.w, rc[g][4 * j4 + 3], zb[g]);
            }
        }
        {
            float2 h2 = *((const float2*)h_lds + 24);  // elems 48,49
            #pragma unroll
            for (int g = 0; g < 4; ++g) {
                za[g] = fmaf(h2.x, rc[g][48], za[g]);
                zb[g] = fmaf(h2.y, rc[g][49], zb[g]);
            }
        }

        float z[4];
        #pragma unroll
        for (int g = 0; g < 4; ++g) {
            float zx = fmaf(x4.x, kc[g][0],
                       fmaf(x4.y, kc[g][1],
                       fmaf(x4.z, kc[g][2],
                       fmaf(x4.w, kc[g][3], bz[g]))));
            z[g] = zx + za[g] + zb[g];
        }

        float ig = sigmoid_fast(z[0]);
        float fg = sigmoid_fast(z[1]);
        float gg = tanh_fast(z[2]);
        float og = sigmoid_fast(z[3]);
        c = fmaf(fg, c, ig * gg);
        float hnew = og * tanh_fast(c);
        if (act_lane) h_lds[l] = hnew;
        // no barrier: single wave, LDS ops in order, compiler inserts lgkmcnt
    }

    // ---- 5 output heads (lanes 0..4), once ----
    if (l < 5) {
        const float* w  = (l == 0) ? w_dv : (l == 1) ? w_dt :
                          (l == 2) ? w_mj : (l == 3) ? w_ma : w_mi;
        const float* bb = (l == 0) ? b_dv : (l == 1) ? b_dt :
                          (l == 2) ? b_mj : (l == 3) ? b_ma : b_mi;
        float s = bb[0];
        #pragma unroll
        for (int j = 0; j < U; ++j) s = fmaf(h_lds[j], w[j], s);
        float v;
        if (l == 0)      v = param_act(s, 15.0f, 35.0f);
        else if (l == 1) v = param_act(s, 0.5f, 3.0f);
        else if (l == 2) v = fmaxf(s, 0.0f);
        else if (l == 3) v = param_act(s, 0.5f, 3.0f);
        else             v = param_act(s, 0.5f, 4.0f);
        idm[l] = v;
        out[BB * TT + b * 5 + l] = v;
    }

    // ---- IDM physics over T (parallel across the wave) ----
    const float desired_v    = idm[0];
    const float desired_tgap = idm[1];
    const float min_jamx     = idm[2];
    const float max_act      = idm[3];
    const float min_act      = idm[4];
    const float inv_tsab = 1.0f / (2.0f * sqrtf(max_act * min_act));
    const float inv_dv   = 1.0f / desired_v;

    const float4* __restrict__ sb4 = (const float4*)(state + (size_t)b * TT * 4);
    for (int t = l; t < TT; t += 64) {
        float4 s4 = sb4[t];
        float vel = s4.x;
        float dv  = s4.z;
        float dx  = s4.w;
        float dgap = fmaf(desired_tgap, vel, fmaf(vel * dv, inv_tsab, min_jamx));
        float r1 = vel * inv_dv;
        r1 = r1 * r1;
        r1 = r1 * r1;            // ^4
        float r2 = dgap / dx;
        r2 = r2 * r2;            // ^2
        out[b * TT + t] = max_act * (1.0f - (r1 + r2));
    }
}

extern "C" void kernel_launch(void* const* d_in, const int* in_sizes, int n_in,
                              void* d_out, int out_size, void* d_ws, size_t ws_size,
                              hipStream_t stream) {
    const float* x      = (const float*)d_in[0];
    const float* state  = (const float*)d_in[1];
    const float* kern   = (const float*)d_in[2];
    const float* rec    = (const float*)d_in[3];
    const float* bias   = (const float*)d_in[4];
    const float* w_dv   = (const float*)d_in[5];
    const float* b_dv   = (const float*)d_in[6];
    const float* w_dt   = (const float*)d_in[7];
    const float* b_dt   = (const float*)d_in[8];
    const float* w_mj   = (const float*)d_in[9];
    const float* b_mj   = (const float*)d_in[10];
    const float* w_ma   = (const float*)d_in[11];
    const float* b_ma   = (const float*)d_in[12];
    const float* w_mi   = (const float*)d_in[13];
    const float* b_mi   = (const float*)d_in[14];
    float* out = (float*)d_out;

    encoder_kernel<<<BB, 64, 0, stream>>>(
        x, state, kern, rec, bias,
        w_dv, b_dv, w_dt, b_dt, w_mj, b_mj, w_ma, b_ma, w_mi, b_mi,
        out);
}

// Round 3
// 63.504 us; speedup vs baseline: 1.3812x; 1.3812x over previous
//
#include <hip/hip_runtime.h>
#include <math.h>

#define U 50
#define TT 100
#define BB 256

__device__ __forceinline__ float sigmoid_fast(float x) {
    return 1.0f / (1.0f + __expf(-x));
}
__device__ __forceinline__ float tanh_fast(float x) {
    float e = __expf(2.0f * x);
    return 1.0f - 2.0f / (e + 1.0f);
}
__device__ __forceinline__ float param_act(float x, float mn, float mx) {
    float scale = 0.5f * (mx - mn);
    return tanh_fast(x) * scale + mn + scale;
}

// One wave per batch element. Lane l (<50) owns LSTM unit l: all four gate
// columns of rec in REGISTERS (the whole point of this round), gate math
// lane-local, h exchanged via LDS broadcast (no barriers: single wave).
__global__ __launch_bounds__(64, 1) void encoder_kernel(
    const float* __restrict__ x,        // (B,T,4)
    const float* __restrict__ state,    // (B,T,4)
    const float* __restrict__ kernel,   // (4,200)
    const float* __restrict__ rec,      // (50,200)
    const float* __restrict__ bias,     // (200,)
    const float* __restrict__ w_dv, const float* __restrict__ b_dv,
    const float* __restrict__ w_dt, const float* __restrict__ b_dt,
    const float* __restrict__ w_mj, const float* __restrict__ b_mj,
    const float* __restrict__ w_ma, const float* __restrict__ b_ma,
    const float* __restrict__ w_mi, const float* __restrict__ b_mi,
    float* __restrict__ out)            // act_seq (B*T) then idm (B*5)
{
    const int b = blockIdx.x;
    const int l = threadIdx.x;
    const int cl = (l < U) ? l : (U - 1);   // clamped column lane (no cndmask per weight)

    __shared__ __align__(16) float h_lds[52];   // 50 + 2 pad (pad stays 0)
    __shared__ float idm[8];

    // rc[g*50+j] = rec[j][g*50+cl]  -- 200 registers, fully static indexing
    float rc[200];
    #pragma unroll
    for (int g = 0; g < 4; ++g)
        #pragma unroll
        for (int j = 0; j < U; ++j)
            rc[g * U + j] = rec[j * 200 + g * U + cl];

    float kc[16];
    #pragma unroll
    for (int g = 0; g < 4; ++g)
        #pragma unroll
        for (int f = 0; f < 4; ++f)
            kc[g * 4 + f] = kernel[f * 200 + g * U + cl];

    float bz[4];
    #pragma unroll
    for (int g = 0; g < 4; ++g) bz[g] = bias[g * U + cl];

    if (l < 52) h_lds[l] = 0.0f;
    float c = 0.0f;

    const float4* __restrict__ xb4 = (const float4*)(x + (size_t)b * TT * 4);
    const float4* __restrict__ h4p = (const float4*)h_lds;

    float4 x4 = xb4[0];

    for (int t = 0; t < TT; ++t) {
        // prefetch next x (hides global latency under this step)
        float4 x4n = xb4[(t + 1 < TT) ? (t + 1) : t];

        // x-part first: independent of h, fills the LDS-read latency shadow
        float z[4];
        #pragma unroll
        for (int g = 0; g < 4; ++g) {
            z[g] = fmaf(x4.x, kc[g * 4 + 0],
                   fmaf(x4.y, kc[g * 4 + 1],
                   fmaf(x4.z, kc[g * 4 + 2],
                   fmaf(x4.w, kc[g * 4 + 3], bz[g]))));
        }

        float za[4] = {0.f, 0.f, 0.f, 0.f};
        float zb[4] = {0.f, 0.f, 0.f, 0.f};
        #pragma unroll
        for (int j4 = 0; j4 < 12; ++j4) {
            float4 h4 = h4p[j4];             // ds_read_b128 broadcast
            #pragma unroll
            for (int g = 0; g < 4; ++g) {
                za[g] = fmaf(h4.x, rc[g * U + 4 * j4 + 0], za[g]);
                zb[g] = fmaf(h4.y, rc[g * U + 4 * j4 + 1], zb[g]);
                za[g] = fmaf(h4.z, rc[g * U + 4 * j4 + 2], za[g]);
                zb[g] = fmaf(h4.w, rc[g * U + 4 * j4 + 3], zb[g]);
            }
        }
        {
            float2 h2 = *((const float2*)h_lds + 24);  // elems 48,49
            #pragma unroll
            for (int g = 0; g < 4; ++g) {
                za[g] = fmaf(h2.x, rc[g * U + 48], za[g]);
                zb[g] = fmaf(h2.y, rc[g * U + 49], zb[g]);
            }
        }
        #pragma unroll
        for (int g = 0; g < 4; ++g) z[g] += za[g] + zb[g];

        float ig = sigmoid_fast(z[0]);
        float fg = sigmoid_fast(z[1]);
        float gg = tanh_fast(z[2]);
        float og = sigmoid_fast(z[3]);
        c = fmaf(fg, c, ig * gg);
        float hnew = og * tanh_fast(c);
        if (l < U) h_lds[l] = hnew;
        x4 = x4n;
        // no barrier: single wave, in-order LDS + compiler lgkmcnt
    }

    // ---- 5 output heads (lanes 0..4) ----
    if (l < 5) {
        const float* w  = (l == 0) ? w_dv : (l == 1) ? w_dt :
                          (l == 2) ? w_mj : (l == 3) ? w_ma : w_mi;
        const float* bb = (l == 0) ? b_dv : (l == 1) ? b_dt :
                          (l == 2) ? b_mj : (l == 3) ? b_ma : b_mi;
        float s = bb[0];
        #pragma unroll
        for (int j = 0; j < U; ++j) s = fmaf(h_lds[j], w[j], s);
        float v;
        if (l == 0)      v = param_act(s, 15.0f, 35.0f);
        else if (l == 1) v = param_act(s, 0.5f, 3.0f);
        else if (l == 2) v = fmaxf(s, 0.0f);
        else if (l == 3) v = param_act(s, 0.5f, 3.0f);
        else             v = param_act(s, 0.5f, 4.0f);
        idm[l] = v;
        out[BB * TT + b * 5 + l] = v;
    }

    // ---- IDM physics over T ----
    const float desired_v    = idm[0];
    const float desired_tgap = idm[1];
    const float min_jamx     = idm[2];
    const float max_act      = idm[3];
    const float min_act      = idm[4];
    const float inv_tsab = 1.0f / (2.0f * sqrtf(max_act * min_act));
    const float inv_dv   = 1.0f / desired_v;

    const float4* __restrict__ sb4 = (const float4*)(state + (size_t)b * TT * 4);
    for (int t = l; t < TT; t += 64) {
        float4 s4 = sb4[t];
        float vel = s4.x;
        float dv  = s4.z;
        float dx  = s4.w;
        float dgap = fmaf(desired_tgap, vel, fmaf(vel * dv, inv_tsab, min_jamx));
        float r1 = vel * inv_dv;
        r1 = r1 * r1;
        r1 = r1 * r1;            // ^4
        float r2 = dgap / dx;
        r2 = r2 * r2;            // ^2
        out[b * TT + t] = max_act * (1.0f - (r1 + r2));
    }
}

extern "C" void kernel_launch(void* const* d_in, const int* in_sizes, int n_in,
                              void* d_out, int out_size, void* d_ws, size_t ws_size,
                              hipStream_t stream) {
    const float* x      = (const float*)d_in[0];
    const float* state  = (const float*)d_in[1];
    const float* kern   = (const float*)d_in[2];
    const float* rec    = (const float*)d_in[3];
    const float* bias   = (const float*)d_in[4];
    const float* w_dv   = (const float*)d_in[5];
    const float* b_dv   = (const float*)d_in[6];
    const float* w_dt   = (const float*)d_in[7];
    const float* b_dt   = (const float*)d_in[8];
    const float* w_mj   = (const float*)d_in[9];
    const float* b_mj   = (const float*)d_in[10];
    const float* w_ma   = (const float*)d_in[11];
    const float* b_ma   = (const float*)d_in[12];
    const float* w_mi   = (const float*)d_in[13];
    const float* b_mi   = (const float*)d_in[14];
    float* out = (float*)d_out;

    encoder_kernel<<<BB, 64, 0, stream>>>(
        x, state, kern, rec, bias,
        w_dv, b_dv, w_dt, b_dt, w_mj, b_mj, w_ma, b_ma, w_mi, b_mi,
        out);
}